// Round 7
// baseline (286.409 us; speedup 1.0000x reference)
//
#include <hip/hip_runtime.h>

// OU Euler-Maruyama: x_{i+1} = a*x_i + b_i,  a = 1 - gamma*dt (per-chain const),
// b_i = gamma*mu*dt + sigma*sqrt(dt)*eps_i.
//
// Burst-load segment scan, ONE 512-thread block (8 waves) per chain; wave w
// owns contiguous segment [2560w, 2560w+2560) (wave 7 ragged: 2080 real).
//
// R6 post-mortem: VGPR_Count=44 proved the compiler SANK the burst loads into
// phase 1 and REMATERIALIZED phase 2's inputs by re-loading (legal: noise is
// const __restrict__). The intended 10-deep read pipeline never existed; the
// kernel stayed latency-bound at ~2.5 TB/s. This version pins all 40 loaded
// floats with empty inline-asm ("+v") after the load loop (forces simultaneous
// materialization -> true 10 KB/wave in flight) and re-pins after phase 1 so
// phase 2 is served from registers, not re-loads. Noise is read EXACTLY once.
//
//  phase 1: per-lane weighted fold of the segment offset + one shfl_xor
//           butterfly reduce; lane 0 -> LDS (8 floats).
//  barrier (single; its vmcnt drain is free - all loads already consumed).
//  prefix:  all waves walk the 8 LDS values -> segment-start state.
//  phase 2: per round: uniform-weight wave scan (1 shfl + 1 fma per step),
//           position via Aex=a^(4 lane), 4 outputs, full-line NT store.

#define T_STEPS 20000
#define M_PATHS 64
#define NWAVES  8
#define BLOCK   (NWAVES * 64)           // 512
#define SEG     2560                    // nominal steps per wave; 8*2560=20480
#define ROUNDS  10                      // SEG / 256
#define DT      0.01f
#define SQRT_DT 0.1f

typedef float f32x4 __attribute__((ext_vector_type(4)));

__global__ __launch_bounds__(BLOCK, 4) void ou_scan_kernel(
    const float* __restrict__ theta,
    const float* __restrict__ noise,
    float* __restrict__ out)
{
    __shared__ float sS[NWAVES];

    const int tid   = threadIdx.x;
    const int wave  = tid >> 6;
    const int lane  = tid & 63;
    const int chain = blockIdx.x;            // 0 .. 2047
    const int n     = chain >> 6;            // theta row

    const float gamma = theta[n * 4 + 0];
    const float mu    = theta[n * 4 + 1];
    const float sigma = theta[n * 4 + 2];
    const float x0    = theta[n * 4 + 3];

    const float a    = 1.0f - gamma * DT;
    const float gmdt = gamma * mu * DT;
    const float ssd  = sigma * SQRT_DT;

    // powers of a (uniform per block)
    const float a2    = a * a;
    const float a4    = a2 * a2;
    const float a8    = a4 * a4;
    const float a16   = a8 * a8;
    const float a32   = a16 * a16;
    const float a64   = a32 * a32;
    const float a128  = a64 * a64;
    const float a256  = a128 * a128;   // per-round multiplier
    const float a512  = a256 * a256;
    const float a1024 = a512 * a512;
    const float a2048 = a1024 * a1024;
    const float a2560 = a2048 * a512;  // per-segment multiplier

    // phase-1 reduction weight: a^(4*(63-lane))
    const int li = lane ^ 63;
    float wred = 1.f;
    if (li & 1)  wred *= a4;
    if (li & 2)  wred *= a8;
    if (li & 4)  wred *= a16;
    if (li & 8)  wred *= a32;
    if (li & 16) wred *= a64;
    if (li & 32) wred *= a128;

    // in-round lane position multiplier: a^(4*lane)
    float Aex = 1.f;
    if (lane & 1)  Aex *= a4;
    if (lane & 2)  Aex *= a8;
    if (lane & 4)  Aex *= a16;
    if (lane & 8)  Aex *= a32;
    if (lane & 16) Aex *= a64;
    if (lane & 32) Aex *= a128;

    // per-wave exclusive multiplier (via walk below) uses a2560 directly.

    const float* __restrict__ np_ = noise + (size_t)chain * T_STEPS;
    float* __restrict__       op_ = out   + (size_t)chain * T_STEPS;
    const int segb = wave * SEG;
    const int loff = lane << 2;

    // ---- burst load: entire segment, 10 independent coalesced float4s ----
    float4 c[ROUNDS];
    #pragma unroll
    for (int r = 0; r < ROUNDS; ++r) {
        const int e = segb + (r << 8) + loff;
        if (e + 4 <= T_STEPS) {
            c[r] = *(const float4*)(np_ + e);
        } else {
            c[r] = make_float4(0.f, 0.f, 0.f, 0.f);
        }
    }
    // PIN: force all 40 values simultaneously live in VGPRs here. Without
    // this the compiler sinks the loads and re-loads in phase 2 (R6: VGPR=44).
    #pragma unroll
    for (int r = 0; r < ROUNDS; ++r) {
        asm volatile("" : "+v"(c[r].x), "+v"(c[r].y), "+v"(c[r].z), "+v"(c[r].w));
    }

    // ---- phase 1: segment offset S_w (per-lane fold, one wave reduce) ----
    float acc = 0.f;
    #pragma unroll
    for (int r = 0; r < ROUNDS; ++r) {
        const int  e  = segb + (r << 8) + loff;
        const bool ar = (e + 4 <= T_STEPS);
        const float b0 = fmaf(ssd, c[r].x, gmdt);
        const float b1 = fmaf(ssd, c[r].y, gmdt);
        const float b2 = fmaf(ssd, c[r].z, gmdt);
        const float b3 = fmaf(ssd, c[r].w, gmdt);
        float p = b0;
        p = fmaf(p, a, b1);
        p = fmaf(p, a, b2);
        p = fmaf(p, a, b3);
        acc = fmaf(acc, a256, ar ? p : 0.f);
    }
    {
        float v = wred * acc;
        v += __shfl_xor(v, 1);
        v += __shfl_xor(v, 2);
        v += __shfl_xor(v, 4);
        v += __shfl_xor(v, 8);
        v += __shfl_xor(v, 16);
        v += __shfl_xor(v, 32);
        if (lane == 0) sS[wave] = v;
    }

    // RE-PIN: keep the noise registers alive across the barrier so phase 2
    // cannot be rematerialized via re-loads.
    #pragma unroll
    for (int r = 0; r < ROUNDS; ++r) {
        asm volatile("" : "+v"(c[r].x), "+v"(c[r].y), "+v"(c[r].z), "+v"(c[r].w));
    }

    __syncthreads();   // the ONLY barrier; all loads already consumed

    // ---- segment-start state for this wave (uniform walk of 8 values) ----
    float xw;
    {
        float xs = x0;
        float my = x0;
        #pragma unroll
        for (int v = 0; v < NWAVES; ++v) {
            if (wave == v) my = xs;
            xs = fmaf(a2560, xs, sS[v]);
        }
        xw = my;   // state entering round 0 of this wave's segment
    }

    // ---- phase 2: replay rounds from registers, scan + store ----
    #pragma unroll
    for (int r = 0; r < ROUNDS; ++r) {
        const int  e  = segb + (r << 8) + loff;
        const bool ar = (e + 4 <= T_STEPS);

        const float b0 = fmaf(ssd, c[r].x, gmdt);
        const float b1 = fmaf(ssd, c[r].y, gmdt);
        const float b2 = fmaf(ssd, c[r].z, gmdt);
        const float b3 = fmaf(ssd, c[r].w, gmdt);
        float p = b0;
        p = fmaf(p, a, b1);
        p = fmaf(p, a, b2);
        p = fmaf(p, a, b3);

        float B = ar ? p : 0.f;

        // uniform-weight inclusive scan (1 shfl + 1 fma per step)
        {
            float t;
            t = __shfl_up(B, 1);  if (lane >= 1)  B = fmaf(a4,   t, B);
            t = __shfl_up(B, 2);  if (lane >= 2)  B = fmaf(a8,   t, B);
            t = __shfl_up(B, 4);  if (lane >= 4)  B = fmaf(a16,  t, B);
            t = __shfl_up(B, 8);  if (lane >= 8)  B = fmaf(a32,  t, B);
            t = __shfl_up(B, 16); if (lane >= 16) B = fmaf(a64,  t, B);
            t = __shfl_up(B, 32); if (lane >= 32) B = fmaf(a128, t, B);
        }

        float Bex = __shfl_up(B, 1);
        if (lane == 0) Bex = 0.f;
        float x = fmaf(Aex, xw, Bex);          // state entering this lane

        const float B63 = __shfl(B, 63);
        xw = fmaf(a256, xw, B63);              // round carry (register chain)

        if (ar) {
            f32x4 o;
            x = fmaf(a, x, b0); o.x = x;
            x = fmaf(a, x, b1); o.y = x;
            x = fmaf(a, x, b2); o.z = x;
            x = fmaf(a, x, b3); o.w = x;
            __builtin_nontemporal_store(o, (f32x4*)(op_ + e));
        }
    }
}

extern "C" void kernel_launch(void* const* d_in, const int* in_sizes, int n_in,
                              void* d_out, int out_size, void* d_ws, size_t ws_size,
                              hipStream_t stream) {
    const float* theta = (const float*)d_in[0];
    const float* noise = (const float*)d_in[1];
    float* out = (float*)d_out;

    const int chains = in_sizes[1] / T_STEPS;   // 2048
    ou_scan_kernel<<<chains, BLOCK, 0, stream>>>(theta, noise, out);
}